// Round 1
// baseline (544.472 us; speedup 1.0000x reference)
//
#include <hip/hip_runtime.h>
#include <math.h>

#define N_OPS 320

__global__ __launch_bounds__(256) void mahjong_kernel(
    const float* __restrict__ meta,        // (N,6)
    const float* __restrict__ wall,        // (N,34,5)
    const float* __restrict__ tile_prep,   // (N,320,34,7)
    const float* __restrict__ fan_prep,    // (N,320,80)
    const float* __restrict__ redundant,   // (N,320,34)
    const float* __restrict__ W_throw,     // (11)
    const float* __restrict__ b_throw,     // (1)
    const float* __restrict__ fan_coeff,   // (80)
    const float* __restrict__ fan_mult,    // (80)
    const float* __restrict__ tile_coeff,  // (34)
    float* __restrict__ out_max,           // (N,5)
    float* __restrict__ out_weighted,      // (N,34)
    int n)
{
    const int blk  = blockIdx.x;
    const int b    = blk / 5;
    const int g    = blk % 5;
    const int tid  = threadIdx.x;
    const int wave = tid >> 6;
    const int lane = tid & 63;

    __shared__ float prob_sm[34];
    __shared__ float fc_sm[80];
    __shared__ float final_sm[64];
    __shared__ float acc_sm[4 * 34];

    // ---- stage 1: prob_throw (Linear(11,1)) and fused fan coeff into LDS ----
    if (tid < 34) {
        float acc = b_throw[0];
        #pragma unroll
        for (int j = 0; j < 6; ++j) acc += meta[(size_t)b * 6 + j] * W_throw[j];
        const float* w = wall + ((size_t)b * 34 + tid) * 5;
        #pragma unroll
        for (int j = 0; j < 5; ++j) acc += w[j] * W_throw[6 + j];
        prob_sm[tid] = acc;
    }
    if (tid >= 64 && tid < 144) {
        int f = tid - 64;
        fc_sm[f] = fan_coeff[f] * fan_mult[f];
    }
    __syncthreads();

    // ---- stage 2: each wave computes final_prob_throw for 16 o's ----
    const int o0 = g * 64;
    for (int i = 0; i < 16; ++i) {
        int o_local = wave * 16 + i;
        size_t row = (size_t)b * N_OPS + o0 + o_local;

        float ts = 1.0f;  // identity for product reduce (lanes >= 34)
        if (lane < 34) {
            const float* tp = tile_prep + row * 34 * 7 + (size_t)lane * 7;
            float c0 = tp[0], c1 = tp[1], c2 = tp[2], c3 = tp[3];
            float c4 = tp[4], c5 = tp[5], c6 = tp[6];
            float t1 = c0 * powf(prob_sm[lane], c1);
            float t2 = c3 * c2 / c4;
            if (isnan(t2)) t2 = 0.0f;
            else if (isinf(t2)) t2 = copysignf(3.4028234663852886e38f, t2);
            ts = t1 + c6 + t2 * c5;
        }
        #pragma unroll
        for (int s = 1; s < 64; s <<= 1) ts *= __shfl_xor(ts, s);

        const float* fp = fan_prep + row * 80;
        float fv = fp[lane] * fc_sm[lane];
        if (lane < 16) fv += fp[64 + lane] * fc_sm[64 + lane];
        #pragma unroll
        for (int s = 1; s < 64; s <<= 1) fv += __shfl_xor(fv, s);

        if (lane == 0) final_sm[o_local] = ts * 100.0f * fv;
    }
    __syncthreads();

    // ---- stage 3: tile_bound_winrate partials (lane = tile idx) ----
    if (lane < 34) {
        float part = 0.0f;
        #pragma unroll 4
        for (int i = 0; i < 16; ++i) {
            int o_local = wave * 16 + i;
            size_t row = (size_t)b * N_OPS + o0 + o_local;
            part += redundant[row * 34 + lane] * final_sm[o_local];
        }
        acc_sm[wave * 34 + lane] = part;
    }
    __syncthreads();

    // ---- stage 4: combine + outputs (wave 0 only) ----
    if (wave == 0) {
        if (g == 0) {
            if (lane < 34) {
                float tbw = acc_sm[lane] + acc_sm[34 + lane] +
                            acc_sm[68 + lane] + acc_sm[102 + lane];
                out_weighted[(size_t)b * 34 + lane] = tbw * tile_coeff[lane];
            }
            // final_prob_ops[b][0] = sum of finals over the 64 o's of group 0
            float fs = final_sm[lane];
            #pragma unroll
            for (int s = 1; s < 64; s <<= 1) fs += __shfl_xor(fs, s);
            if (lane == 0) out_max[(size_t)b * 5] = fs;
        } else {
            float m = -INFINITY;
            if (lane < 34) m = acc_sm[lane] + acc_sm[34 + lane] +
                               acc_sm[68 + lane] + acc_sm[102 + lane];
            #pragma unroll
            for (int s = 1; s < 64; s <<= 1) m = fmaxf(m, __shfl_xor(m, s));
            if (lane == 0) out_max[(size_t)b * 5 + g] = m;
        }
    }
}

extern "C" void kernel_launch(void* const* d_in, const int* in_sizes, int n_in,
                              void* d_out, int out_size, void* d_ws, size_t ws_size,
                              hipStream_t stream) {
    const float* meta       = (const float*)d_in[0];
    const float* wall       = (const float*)d_in[1];
    const float* tile_prep  = (const float*)d_in[2];
    const float* fan_prep   = (const float*)d_in[3];
    const float* redundant  = (const float*)d_in[4];
    // d_in[5] count_prep, d_in[6] chi_peng_count_remain: unused by reference
    const float* W_throw    = (const float*)d_in[7];
    const float* b_throw    = (const float*)d_in[8];
    const float* fan_coeff  = (const float*)d_in[9];
    const float* fan_mult   = (const float*)d_in[10];
    const float* tile_coeff = (const float*)d_in[11];

    int n = in_sizes[0] / 6;
    float* out_max      = (float*)d_out;            // (n,5)
    float* out_weighted = out_max + (size_t)n * 5;  // (n,34)

    dim3 grid(n * 5), block(256);
    hipLaunchKernelGGL(mahjong_kernel, grid, block, 0, stream,
                       meta, wall, tile_prep, fan_prep, redundant,
                       W_throw, b_throw, fan_coeff, fan_mult, tile_coeff,
                       out_max, out_weighted, n);
}